// Round 8
// baseline (85.641 us; speedup 1.0000x reference)
//
#include <hip/hip_runtime.h>
#include <hip/hip_bf16.h>
#include <math.h>

#define B_ 16
#define S_ 8192
#define H_ 256
#define NBLK 32      // scores blocks per batch row
#define TILE_R 32    // s-rows per tile
#define T_PER_BLK 8  // tiles per block -> block covers 256 rows
#define LROW 264     // shorts per LDS row: 256 + 8 pad (132 dwords, 33 slots)

using bf16x8 = __attribute__((ext_vector_type(8))) short;
using f32x4 = __attribute__((ext_vector_type(4))) float;

#define LOG2E2 2.885390082f  // 2*log2(e)

// fp32 -> bf16 RNE (scalar, for prep one-time packing)
__device__ inline short f2bf(float x) {
  union {
    float f;
    unsigned u;
  } v;
  v.f = x;
  unsigned r = v.u + 0x7FFFu + ((v.u >> 16) & 1u);
  return (short)(r >> 16);
}

// pack 8 fp32 -> 8 bf16 via v_cvt_pk_bf16_f32
__device__ inline bf16x8 pack8(float4 a, float4 b) {
  union {
    __hip_bfloat162 h[4];
    bf16x8 v;
  } u;
  u.h[0] = __float22bfloat162_rn(make_float2(a.x, a.y));
  u.h[1] = __float22bfloat162_rn(make_float2(a.z, a.w));
  u.h[2] = __float22bfloat162_rn(make_float2(b.x, b.y));
  u.h[3] = __float22bfloat162_rn(make_float2(b.z, b.w));
  return u.v;
}

// ---------------------------------------------------------------------------
// prep: blocks 0..31 pack W2 into MFMA B-fragment-major bf16; blocks 32..47:
// h1[b][k] = sum_h hidden[b][h]*W1[k][h]
// ---------------------------------------------------------------------------
__global__ __launch_bounds__(256) void prep_kernel(
    const float* __restrict__ hidden, const float* __restrict__ W1,
    const float* __restrict__ W2, short* __restrict__ W2f,
    float* __restrict__ h1) {
  const int blk = blockIdx.x;
  const int t = threadIdx.x;
  if (blk < 32) {
    const int gid = blk * 256 + t;  // 0..8191
    const int l = gid & 63;
    const int j0 = (gid >> 6) & 15;
    const int ks = gid >> 10;  // 0..7
    const int row = j0 * 16 + (l & 15);
    const int col = ks * 32 + (l >> 4) * 8;
    const float* wp = W2 + row * H_ + col;
    bf16x8 out;
#pragma unroll
    for (int i = 0; i < 8; ++i) out[i] = f2bf(wp[i]);
    *(bf16x8*)(W2f + (size_t)gid * 8) = out;
  } else {
    const int b = blk - 32;
    const float* hrow = hidden + b * H_;
    const float* wrow = W1 + t * H_;
    float acc = 0.f;
#pragma unroll 8
    for (int h = 0; h < H_; ++h) acc += hrow[h] * wrow[h];
    h1[b * H_ + t] = acc;
  }
}

// ---------------------------------------------------------------------------
// scores_ctx: fused GEMM + tanh/V-dot + UNNORMALIZED softmax-context.
// 512 thr = 8 waves, weight-stationary (wave w owns j0 {2w,2w+1} in regs).
// Epilogue algebra: sum_j tanh(x_j)*V_j = Vsum - 2*sum_j V_j*rcp(exp2(
// 2*log2e*x_j)+1); per element only 3 VALU + 2 TRANS.
// Two __syncthreads per tile:
//   MFMA(albuf[cur]) -> epilogue -> pcomb -> B1
//   -> [stage next tile into albuf[cur^1] || distributed combine -> avec]
//   -> B2 -> PV from albuf[cur] -> next iter.
// ---------------------------------------------------------------------------
__global__ __launch_bounds__(512, 4) void scores_ctx_kernel(
    const float* __restrict__ enc, const short* __restrict__ W2f,
    const float* __restrict__ h1, const float* __restrict__ V,
    float* __restrict__ expsc, float* __restrict__ c_blk,
    float* __restrict__ l_blk) {
  __shared__ __align__(16) short albuf[2][TILE_R * LROW];  // 2 x 16.5 KiB
  __shared__ float pcomb[8][33];
  __shared__ float avec[TILE_R];
  __shared__ float2 clds2[4][129];
  __shared__ float lsum[8];

  const int tid = threadIdx.x;
  const int w = tid >> 6;
  const int l = tid & 63;
  const int lo = l & 15;
  const int hi = l >> 4;
  const int bid = blockIdx.x;
  const int b = bid >> 5;
  const int blk = bid & 31;
  const int s_base = blk * (TILE_R * T_PER_BLK);

  // --- one-time: B fragments into registers (j0 = 2w, 2w+1) ---
  const bf16x8* bbase = (const bf16x8*)W2f;
  bf16x8 bfrag[8][2];
#pragma unroll
  for (int ks = 0; ks < 8; ++ks)
#pragma unroll
    for (int jj = 0; jj < 2; ++jj)
      bfrag[ks][jj] = bbase[(ks * 16 + (2 * w + jj)) * 64 + l];

  float Vv0 = V[(2 * w) * 16 + lo];
  float Vv1 = V[(2 * w + 1) * 16 + lo];
  // d_j = h1_j * 2log2e (folds the +h1 add and the 2x*log2e mul into 1 fma)
  float d0 = h1[b * H_ + (2 * w) * 16 + lo] * LOG2E2;
  float d1 = h1[b * H_ + (2 * w + 1) * 16 + lo] * LOG2E2;
  // wave-constant Vsum = sum over this wave's 32 j of V[j]
  float Vsum = Vv0 + Vv1;
  Vsum += __shfl_xor(Vsum, 1, 16);
  Vsum += __shfl_xor(Vsum, 2, 16);
  Vsum += __shfl_xor(Vsum, 4, 16);
  Vsum += __shfl_xor(Vsum, 8, 16);

  // staging ids: thread covers rows r0, r0+16 at col chunk kc0*8
  const int r0 = tid >> 5;   // 0..15
  const int kc0 = tid & 31;  // 8-float col chunk
  const float4* gsrc = (const float4*)(enc + (size_t)b * S_ * H_);

  // PV ids: thread covers dword-col cp (h = 2cp, 2cp+1), rows rg*8..rg*8+7
  const int rg = tid >> 7;   // 0..3
  const int cp = tid & 127;  // dword column
  float c0 = 0.f, c1 = 0.f, l_part = 0.f;

  // prologue: stage tile 0
  {
    size_t gi0 = ((size_t)(s_base + r0) * (H_ / 4)) + kc0 * 2;
    size_t gi1 = ((size_t)(s_base + r0 + 16) * (H_ / 4)) + kc0 * 2;
    float4 a0 = gsrc[gi0], a1 = gsrc[gi0 + 1];
    float4 b0 = gsrc[gi1], b1 = gsrc[gi1 + 1];
    *(bf16x8*)&albuf[0][r0 * LROW + kc0 * 8] = pack8(a0, a1);
    *(bf16x8*)&albuf[0][(r0 + 16) * LROW + kc0 * 8] = pack8(b0, b1);
  }
  __syncthreads();

  const int b0s = lo & 1;
  const int b1s = (lo >> 1) & 1;
  const int b2s = (lo >> 2) & 1;

  for (int t = 0; t < T_PER_BLK; ++t) {
    const int cur = t & 1;

    // issue next tile's global loads (complete under MFMA + epilogue)
    float4 na0, na1, nb0, nb1;
    if (t + 1 < T_PER_BLK) {
      size_t gi0 =
          ((size_t)(s_base + (t + 1) * TILE_R + r0) * (H_ / 4)) + kc0 * 2;
      size_t gi1 =
          ((size_t)(s_base + (t + 1) * TILE_R + r0 + 16) * (H_ / 4)) + kc0 * 2;
      na0 = gsrc[gi0];
      na1 = gsrc[gi0 + 1];
      nb0 = gsrc[gi1];
      nb1 = gsrc[gi1 + 1];
    }

    // --- MFMA phase: A from LDS, B from regs ---
    f32x4 acc[2][2];
#pragma unroll
    for (int m = 0; m < 2; ++m)
#pragma unroll
      for (int jj = 0; jj < 2; ++jj) acc[m][jj] = (f32x4){0.f, 0.f, 0.f, 0.f};

    const short* abase = &albuf[cur][lo * LROW + hi * 8];
#pragma unroll
    for (int ks = 0; ks < 8; ++ks) {
      bf16x8 a0 = *(const bf16x8*)(abase + ks * 32);
      bf16x8 a1 = *(const bf16x8*)(abase + 16 * LROW + ks * 32);
      acc[0][0] = __builtin_amdgcn_mfma_f32_16x16x32_bf16(a0, bfrag[ks][0], acc[0][0], 0, 0, 0);
      acc[0][1] = __builtin_amdgcn_mfma_f32_16x16x32_bf16(a0, bfrag[ks][1], acc[0][1], 0, 0, 0);
      acc[1][0] = __builtin_amdgcn_mfma_f32_16x16x32_bf16(a1, bfrag[ks][0], acc[1][0], 0, 0, 0);
      acc[1][1] = __builtin_amdgcn_mfma_f32_16x16x32_bf16(a1, bfrag[ks][1], acc[1][1], 0, 0, 0);
    }

    // --- epilogue: q = sum_j V_j * rcp(exp2(acc*2log2e + d_j) + 1) ---
#define QTERM(m, r)                                                     \
  fmaf(Vv0,                                                             \
       __builtin_amdgcn_rcpf(exp2f(fmaf(acc[m][0][r], LOG2E2, d0)) + 1.f), \
       Vv1 * __builtin_amdgcn_rcpf(                                     \
                 exp2f(fmaf(acc[m][1][r], LOG2E2, d1)) + 1.f))
    float p0 = QTERM(0, 0);
    float p1 = QTERM(0, 1);
    float p2 = QTERM(0, 2);
    float p3 = QTERM(0, 3);
    float p4 = QTERM(1, 0);
    float p5 = QTERM(1, 1);
    float p6 = QTERM(1, 2);
    float p7 = QTERM(1, 3);
#undef QTERM

    // 8-shfl value-split 16-lane reduce of the q's
    float q0 = (b0s ? p1 : p0) + __shfl_xor((b0s ? p0 : p1), 1, 16);
    float q1 = (b0s ? p3 : p2) + __shfl_xor((b0s ? p2 : p3), 1, 16);
    float q2 = (b0s ? p5 : p4) + __shfl_xor((b0s ? p4 : p5), 1, 16);
    float q3 = (b0s ? p7 : p6) + __shfl_xor((b0s ? p6 : p7), 1, 16);
    float r0q = (b1s ? q1 : q0) + __shfl_xor((b1s ? q0 : q1), 2, 16);
    float r1q = (b1s ? q3 : q2) + __shfl_xor((b1s ? q2 : q3), 2, 16);
    float u = (b2s ? r1q : r0q) + __shfl_xor((b2s ? r0q : r1q), 4, 16);
    u += __shfl_xor(u, 8, 16);

    if (lo < 8) {
      const int row = ((lo >> 2) & 1) * 16 + hi * 4 + (lo & 3);
      pcomb[w][row] = fmaf(-2.f, u, Vsum);  // partial score = Vsum - 2q
    }
    __syncthreads();  // B1: pcomb ready

    // stage next tile into the other buffer (overlaps the combine below)
    if (t + 1 < T_PER_BLK) {
      *(bf16x8*)&albuf[cur ^ 1][r0 * LROW + kc0 * 8] = pack8(na0, na1);
      *(bf16x8*)&albuf[cur ^ 1][(r0 + 16) * LROW + kc0 * 8] = pack8(nb0, nb1);
    }

    // distributed combine: wave w, lanes 0..3 -> rows 4w..4w+3
    if (l < 4) {
      const int row = w * 4 + l;
      float s = 0.f;
#pragma unroll
      for (int ww = 0; ww < 8; ++ww) s += pcomb[ww][row];
      float e = exp2f(s * 1.44269504f);
      avec[row] = e;
      expsc[(size_t)b * S_ + s_base + t * TILE_R + row] = e;
      l_part += e;
    }
    __syncthreads();  // B2: avec + staged buffer ready

    // --- PV: c[h] += exp(s) * enc_bf16[s][h] from albuf[cur] ---
    const unsigned* ab32 = (const unsigned*)&albuf[cur][0];
#pragma unroll
    for (int k = 0; k < 8; ++k) {
      const int r = rg * 8 + k;
      unsigned vb = ab32[r * 132 + cp];
      float a = avec[r];
      float he = __uint_as_float(vb << 16);
      float ho = __uint_as_float(vb & 0xFFFF0000u);
      c0 = fmaf(a, he, c0);
      c1 = fmaf(a, ho, c1);
    }
    // no barrier: PV(t) reads complete before this wave's B1(t+1), and
    // stage(t+1) into albuf[cur] happens only after B1(t+1).
  }

  // --- final combines ---
  float lp = l_part;  // nonzero only in lanes 0..3 of each wave
  lp += __shfl_xor(lp, 1);
  lp += __shfl_xor(lp, 2);
  if (l == 0) lsum[w] = lp;
  clds2[rg][cp] = make_float2(c0, c1);
  __syncthreads();
  if (tid < 128) {
    float2 s0 = clds2[0][tid], s1 = clds2[1][tid];
    float2 s2 = clds2[2][tid], s3 = clds2[3][tid];
    float2 r;
    r.x = s0.x + s1.x + s2.x + s3.x;
    r.y = s0.y + s1.y + s2.y + s3.y;
    ((float2*)(c_blk + ((size_t)(b * NBLK + blk)) * H_))[tid] = r;
  }
  if (tid == 0) {
    float ls = 0.f;
#pragma unroll
    for (int ww = 0; ww < 8; ++ww) ls += lsum[ww];
    l_blk[b * NBLK + blk] = ls;
  }
}

// ---------------------------------------------------------------------------
// finish: grid (260, B). bx<4: attn-norm chunk (out2 = expsc/lg);
// bx>=4: h = bx-4: ctx = sum_blk c_blk/lg -> out1 + broadcast out0 row.
// ---------------------------------------------------------------------------
__global__ __launch_bounds__(256) void finish_kernel(
    const float* __restrict__ expsc, const float* __restrict__ l_blk,
    const float* __restrict__ c_blk, float* __restrict__ out0,
    float* __restrict__ out1, float* __restrict__ out2) {
  const int bx = blockIdx.x;
  const int b = blockIdx.y;
  const int tid = threadIdx.x;
  float lg = 0.f;
#pragma unroll
  for (int j = 0; j < NBLK; ++j) lg += l_blk[b * NBLK + j];
  const float inv = 1.f / lg;

  if (bx < 4) {
    const size_t base = (size_t)b * S_ + bx * 2048;
    const float4* ip = (const float4*)(expsc + base);
    float4* op = (float4*)(out2 + base);
    float4 x0 = ip[tid * 2];
    float4 x1 = ip[tid * 2 + 1];
    float4 y0 = {x0.x * inv, x0.y * inv, x0.z * inv, x0.w * inv};
    float4 y1 = {x1.x * inv, x1.y * inv, x1.z * inv, x1.w * inv};
    op[tid * 2] = y0;
    op[tid * 2 + 1] = y1;
  } else {
    const int h = bx - 4;
    float cs = 0.f;
#pragma unroll
    for (int j = 0; j < NBLK; ++j)
      cs += c_blk[((size_t)(b * NBLK + j)) * H_ + h];
    const float ctx = cs * inv;
    if (tid == 0) out1[b * H_ + h] = ctx;
    float4 vv = {ctx, ctx, ctx, ctx};
    float4* op = (float4*)(out0 + ((size_t)b * H_ + h) * S_);
#pragma unroll 4
    for (int i = tid; i < S_ / 4; i += 256) op[i] = vv;
  }
}

extern "C" void kernel_launch(void* const* d_in, const int* in_sizes, int n_in,
                              void* d_out, int out_size, void* d_ws,
                              size_t ws_size, hipStream_t stream) {
  const float* hidden = (const float*)d_in[0];
  const float* enc = (const float*)d_in[1];
  const float* W1 = (const float*)d_in[2];
  const float* W2 = (const float*)d_in[3];
  const float* V = (const float*)d_in[4];

  float* out0 = (float*)d_out;                // [B,H,S] context tiled
  float* out1 = out0 + (size_t)B_ * H_ * S_;  // [B,H]   context
  float* out2 = out1 + B_ * H_;               // [B,S]   attn

  float* ws = (float*)d_ws;
  short* W2f = (short*)ws;                 // 65536 shorts = 32768 floats
  float* h1 = ws + 32768;                  // 4096
  float* expsc = h1 + B_ * H_;             // B*S = 131072
  float* l_blk = expsc + (size_t)B_ * S_;  // 512
  float* c_blk = l_blk + B_ * NBLK;        // B*NBLK*H = 131072

  prep_kernel<<<48, 256, 0, stream>>>(hidden, W1, W2, W2f, h1);
  scores_ctx_kernel<<<B_ * NBLK, 512, 0, stream>>>(enc, W2f, h1, V, expsc,
                                                   c_blk, l_blk);
  finish_kernel<<<dim3(H_ + 4, B_), 256, 0, stream>>>(expsc, l_blk, c_blk,
                                                      out0, out1, out2);
}

// Round 9
// 80.569 us; speedup vs baseline: 1.0630x; 1.0630x over previous
//
#include <hip/hip_runtime.h>
#include <hip/hip_bf16.h>
#include <math.h>

#define B_ 16
#define S_ 8192
#define H_ 256
#define NBLK 32      // scores blocks per batch row
#define TILE_R 32    // s-rows per tile
#define T_PER_BLK 8  // tiles per block -> block covers 256 rows
#define LROW 264     // shorts per LDS row: 256 + 8 pad (132 dwords, 33 slots)

using bf16x8 = __attribute__((ext_vector_type(8))) short;
using f32x4 = __attribute__((ext_vector_type(4))) float;

// fp32 -> bf16 RNE (scalar, for prep one-time packing)
__device__ inline short f2bf(float x) {
  union {
    float f;
    unsigned u;
  } v;
  v.f = x;
  unsigned r = v.u + 0x7FFFu + ((v.u >> 16) & 1u);
  return (short)(r >> 16);
}

// pack 8 fp32 -> 8 bf16 via v_cvt_pk_bf16_f32
__device__ inline bf16x8 pack8(float4 a, float4 b) {
  union {
    __hip_bfloat162 h[4];
    bf16x8 v;
  } u;
  u.h[0] = __float22bfloat162_rn(make_float2(a.x, a.y));
  u.h[1] = __float22bfloat162_rn(make_float2(a.z, a.w));
  u.h[2] = __float22bfloat162_rn(make_float2(b.x, b.y));
  u.h[3] = __float22bfloat162_rn(make_float2(b.z, b.w));
  return u.v;
}

// tanh(x) = 1 - 2/(exp2(2x*log2e)+1)
__device__ inline float fast_tanh(float x) {
  float e = exp2f(x * 2.885390082f);
  return fmaf(-2.f, __builtin_amdgcn_rcpf(e + 1.f), 1.f);
}

// ---------------------------------------------------------------------------
// prep: blocks 0..31 pack W2 into MFMA B-fragment-major bf16; blocks 32..47:
// h1[b][k] = sum_h hidden[b][h]*W1[k][h]
// ---------------------------------------------------------------------------
__global__ __launch_bounds__(256) void prep_kernel(
    const float* __restrict__ hidden, const float* __restrict__ W1,
    const float* __restrict__ W2, short* __restrict__ W2f,
    float* __restrict__ h1) {
  const int blk = blockIdx.x;
  const int t = threadIdx.x;
  if (blk < 32) {
    const int gid = blk * 256 + t;  // 0..8191
    const int l = gid & 63;
    const int j0 = (gid >> 6) & 15;
    const int ks = gid >> 10;  // 0..7
    const int row = j0 * 16 + (l & 15);
    const int col = ks * 32 + (l >> 4) * 8;
    const float* wp = W2 + row * H_ + col;
    bf16x8 out;
#pragma unroll
    for (int i = 0; i < 8; ++i) out[i] = f2bf(wp[i]);
    *(bf16x8*)(W2f + (size_t)gid * 8) = out;
  } else {
    const int b = blk - 32;
    const float* hrow = hidden + b * H_;
    const float* wrow = W1 + t * H_;
    float acc = 0.f;
#pragma unroll 8
    for (int h = 0; h < H_; ++h) acc += hrow[h] * wrow[h];
    h1[b * H_ + t] = acc;
  }
}

// ---------------------------------------------------------------------------
// scores_ctx: fused GEMM + tanh/V-dot + UNNORMALIZED softmax-context.
// 512 thr = 8 waves, weight-stationary (wave w owns j0 {2w,2w+1} in regs).
// ONE barrier per tile, PV lagged one tile, 4-deep albuf:
//   iter t: [loads(t+1) | MFMA(albuf[t&3]) | epilogue->pcomb[t&1]
//            | stage(t+1)->albuf[(t+1)&3]]  B(t)  [combine->avec[t&1]
//            | PV(t-1) from albuf[(t-1)&3], avec[(t-1)&1]]
// Race audit (>=1 barrier between writer and reader everywhere):
//   MFMA(t) reads albuf[t&3] staged pre-B(t-1)           -> B(t-1) between
//   stage(t+1) vs last reader PV(t-3) (post-B(t-2))      -> B(t-1) between
//   PV(t-1) (post-B(t)) vs next writer stage(t+3)
//     (iter t+2, pre-B(t+2))                             -> B(t+1) between
//   pcomb[t&1]: write pre-B(t), read post-B(t); next
//     same-parity write pre-B(t+2)                       -> B(t+1) between
//   avec[t&1]: write post-B(t), read post-B(t+1); next
//     same-parity write post-B(t+2)                      -> B(t+2) between
// ---------------------------------------------------------------------------
__global__ __launch_bounds__(512, 4) void scores_ctx_kernel(
    const float* __restrict__ enc, const short* __restrict__ W2f,
    const float* __restrict__ h1, const float* __restrict__ V,
    float* __restrict__ expsc, float* __restrict__ c_blk,
    float* __restrict__ l_blk) {
  __shared__ __align__(16) short albuf[4][TILE_R * LROW];  // 66 KiB
  __shared__ float pcomb[2][8][33];
  __shared__ float avec[2][TILE_R];
  __shared__ float2 clds2[4][129];
  __shared__ float lsum[8];

  const int tid = threadIdx.x;
  const int w = tid >> 6;
  const int l = tid & 63;
  const int lo = l & 15;
  const int hi = l >> 4;
  const int bid = blockIdx.x;
  const int b = bid >> 5;
  const int blk = bid & 31;
  const int s_base = blk * (TILE_R * T_PER_BLK);

  // --- one-time: B fragments into registers (j0 = 2w, 2w+1) ---
  const bf16x8* bbase = (const bf16x8*)W2f;
  bf16x8 bfrag[8][2];
#pragma unroll
  for (int ks = 0; ks < 8; ++ks)
#pragma unroll
    for (int jj = 0; jj < 2; ++jj)
      bfrag[ks][jj] = bbase[(ks * 16 + (2 * w + jj)) * 64 + l];

  float h1v[2], Vv[2];
#pragma unroll
  for (int jj = 0; jj < 2; ++jj) {
    h1v[jj] = h1[b * H_ + (2 * w + jj) * 16 + lo];
    Vv[jj] = V[(2 * w + jj) * 16 + lo];
  }

  // staging ids: thread covers rows r0, r0+16 at col chunk kc0*8
  const int r0 = tid >> 5;   // 0..15
  const int kc0 = tid & 31;  // 8-float col chunk
  const float4* gsrc = (const float4*)(enc + (size_t)b * S_ * H_);

  // PV ids: thread covers dword-col cp (h = 2cp, 2cp+1), rows rg*8..rg*8+7
  const int rg = tid >> 7;   // 0..3
  const int cp = tid & 127;  // dword column
  float c0 = 0.f, c1 = 0.f, l_part = 0.f;

  // prologue: stage tile 0 into albuf[0]
  {
    size_t gi0 = ((size_t)(s_base + r0) * (H_ / 4)) + kc0 * 2;
    size_t gi1 = ((size_t)(s_base + r0 + 16) * (H_ / 4)) + kc0 * 2;
    float4 a0 = gsrc[gi0], a1 = gsrc[gi0 + 1];
    float4 b0 = gsrc[gi1], b1 = gsrc[gi1 + 1];
    *(bf16x8*)&albuf[0][r0 * LROW + kc0 * 8] = pack8(a0, a1);
    *(bf16x8*)&albuf[0][(r0 + 16) * LROW + kc0 * 8] = pack8(b0, b1);
  }
  __syncthreads();

  const int b0s = lo & 1;
  const int b1s = (lo >> 1) & 1;
  const int b2s = (lo >> 2) & 1;

  for (int t = 0; t < T_PER_BLK; ++t) {
    const int cur = t & 3;
    const int par = t & 1;

    // issue next tile's global loads (complete under MFMA + epilogue)
    float4 na0, na1, nb0, nb1;
    if (t + 1 < T_PER_BLK) {
      size_t gi0 =
          ((size_t)(s_base + (t + 1) * TILE_R + r0) * (H_ / 4)) + kc0 * 2;
      size_t gi1 =
          ((size_t)(s_base + (t + 1) * TILE_R + r0 + 16) * (H_ / 4)) + kc0 * 2;
      na0 = gsrc[gi0];
      na1 = gsrc[gi0 + 1];
      nb0 = gsrc[gi1];
      nb1 = gsrc[gi1 + 1];
    }

    // --- MFMA phase: A from LDS albuf[cur], B from regs ---
    f32x4 acc[2][2];
#pragma unroll
    for (int m = 0; m < 2; ++m)
#pragma unroll
      for (int jj = 0; jj < 2; ++jj) acc[m][jj] = (f32x4){0.f, 0.f, 0.f, 0.f};

    const short* abase = &albuf[cur][lo * LROW + hi * 8];
#pragma unroll
    for (int ks = 0; ks < 8; ++ks) {
      bf16x8 a0 = *(const bf16x8*)(abase + ks * 32);
      bf16x8 a1 = *(const bf16x8*)(abase + 16 * LROW + ks * 32);
      acc[0][0] = __builtin_amdgcn_mfma_f32_16x16x32_bf16(a0, bfrag[ks][0], acc[0][0], 0, 0, 0);
      acc[0][1] = __builtin_amdgcn_mfma_f32_16x16x32_bf16(a0, bfrag[ks][1], acc[0][1], 0, 0, 0);
      acc[1][0] = __builtin_amdgcn_mfma_f32_16x16x32_bf16(a1, bfrag[ks][0], acc[1][0], 0, 0, 0);
      acc[1][1] = __builtin_amdgcn_mfma_f32_16x16x32_bf16(a1, bfrag[ks][1], acc[1][1], 0, 0, 0);
    }

    // --- epilogue: tanh + V-dot, 8-shfl value-split 16-lane reduce ---
    float p0 = fast_tanh(acc[0][0][0] + h1v[0]) * Vv[0] + fast_tanh(acc[0][1][0] + h1v[1]) * Vv[1];
    float p1 = fast_tanh(acc[0][0][1] + h1v[0]) * Vv[0] + fast_tanh(acc[0][1][1] + h1v[1]) * Vv[1];
    float p2 = fast_tanh(acc[0][0][2] + h1v[0]) * Vv[0] + fast_tanh(acc[0][1][2] + h1v[1]) * Vv[1];
    float p3 = fast_tanh(acc[0][0][3] + h1v[0]) * Vv[0] + fast_tanh(acc[0][1][3] + h1v[1]) * Vv[1];
    float p4 = fast_tanh(acc[1][0][0] + h1v[0]) * Vv[0] + fast_tanh(acc[1][1][0] + h1v[1]) * Vv[1];
    float p5 = fast_tanh(acc[1][0][1] + h1v[0]) * Vv[0] + fast_tanh(acc[1][1][1] + h1v[1]) * Vv[1];
    float p6 = fast_tanh(acc[1][0][2] + h1v[0]) * Vv[0] + fast_tanh(acc[1][1][2] + h1v[1]) * Vv[1];
    float p7 = fast_tanh(acc[1][0][3] + h1v[0]) * Vv[0] + fast_tanh(acc[1][1][3] + h1v[1]) * Vv[1];

    float q0 = (b0s ? p1 : p0) + __shfl_xor((b0s ? p0 : p1), 1, 16);
    float q1 = (b0s ? p3 : p2) + __shfl_xor((b0s ? p2 : p3), 1, 16);
    float q2 = (b0s ? p5 : p4) + __shfl_xor((b0s ? p4 : p5), 1, 16);
    float q3 = (b0s ? p7 : p6) + __shfl_xor((b0s ? p6 : p7), 1, 16);
    float r0q = (b1s ? q1 : q0) + __shfl_xor((b1s ? q0 : q1), 2, 16);
    float r1q = (b1s ? q3 : q2) + __shfl_xor((b1s ? q2 : q3), 2, 16);
    float u = (b2s ? r1q : r0q) + __shfl_xor((b2s ? r0q : r1q), 4, 16);
    u += __shfl_xor(u, 8, 16);

    if (lo < 8) {
      const int row = ((lo >> 2) & 1) * 16 + hi * 4 + (lo & 3);
      pcomb[par][w][row] = u;
    }

    // stage next tile into albuf[(t+1)&3] (pre-barrier)
    if (t + 1 < T_PER_BLK) {
      *(bf16x8*)&albuf[(t + 1) & 3][r0 * LROW + kc0 * 8] = pack8(na0, na1);
      *(bf16x8*)&albuf[(t + 1) & 3][(r0 + 16) * LROW + kc0 * 8] =
          pack8(nb0, nb1);
    }
    __syncthreads();  // B(t): pcomb[par] + albuf[(t+1)&3] ready

    // distributed combine: wave w, lanes 0..3 -> rows 4w..4w+3
    if (l < 4) {
      const int row = w * 4 + l;
      float s = 0.f;
#pragma unroll
      for (int ww = 0; ww < 8; ++ww) s += pcomb[par][ww][row];
      float e = exp2f(s * 1.44269504f);
      avec[par][row] = e;
      expsc[(size_t)b * S_ + s_base + t * TILE_R + row] = e;
      l_part += e;
    }

    // --- PV for tile t-1: c[h] += exp(s) * enc_bf16[s][h] ---
    if (t >= 1) {
      const unsigned* ab32 = (const unsigned*)&albuf[(t - 1) & 3][0];
      const float* av = avec[(t - 1) & 1];
#pragma unroll
      for (int k = 0; k < 8; ++k) {
        const int r = rg * 8 + k;
        unsigned vb = ab32[r * 132 + cp];
        float a = av[r];
        float he = __uint_as_float(vb << 16);
        float ho = __uint_as_float(vb & 0xFFFF0000u);
        c0 = fmaf(a, he, c0);
        c1 = fmaf(a, ho, c1);
      }
    }
  }

  __syncthreads();  // avec[last] fully combined
  // final PV for tile T-1
  {
    const unsigned* ab32 = (const unsigned*)&albuf[(T_PER_BLK - 1) & 3][0];
    const float* av = avec[(T_PER_BLK - 1) & 1];
#pragma unroll
    for (int k = 0; k < 8; ++k) {
      const int r = rg * 8 + k;
      unsigned vb = ab32[r * 132 + cp];
      float a = av[r];
      float he = __uint_as_float(vb << 16);
      float ho = __uint_as_float(vb & 0xFFFF0000u);
      c0 = fmaf(a, he, c0);
      c1 = fmaf(a, ho, c1);
    }
  }

  // --- final combines ---
  float lp = l_part;  // nonzero only in lanes 0..3 of each wave
  lp += __shfl_xor(lp, 1);
  lp += __shfl_xor(lp, 2);
  if (l == 0) lsum[w] = lp;
  clds2[rg][cp] = make_float2(c0, c1);
  __syncthreads();
  if (tid < 128) {
    float2 s0 = clds2[0][tid], s1 = clds2[1][tid];
    float2 s2 = clds2[2][tid], s3 = clds2[3][tid];
    float2 r;
    r.x = s0.x + s1.x + s2.x + s3.x;
    r.y = s0.y + s1.y + s2.y + s3.y;
    ((float2*)(c_blk + ((size_t)(b * NBLK + blk)) * H_))[tid] = r;
  }
  if (tid == 0) {
    float ls = 0.f;
#pragma unroll
    for (int ww = 0; ww < 8; ++ww) ls += lsum[ww];
    l_blk[b * NBLK + blk] = ls;
  }
}

// ---------------------------------------------------------------------------
// finish: grid (260, B). bx<4: attn-norm chunk (out2 = expsc/lg);
// bx>=4: h = bx-4: ctx = sum_blk c_blk/lg -> out1 + broadcast out0 row.
// ---------------------------------------------------------------------------
__global__ __launch_bounds__(256) void finish_kernel(
    const float* __restrict__ expsc, const float* __restrict__ l_blk,
    const float* __restrict__ c_blk, float* __restrict__ out0,
    float* __restrict__ out1, float* __restrict__ out2) {
  const int bx = blockIdx.x;
  const int b = blockIdx.y;
  const int tid = threadIdx.x;
  float lg = 0.f;
#pragma unroll
  for (int j = 0; j < NBLK; ++j) lg += l_blk[b * NBLK + j];
  const float inv = 1.f / lg;

  if (bx < 4) {
    const size_t base = (size_t)b * S_ + bx * 2048;
    const float4* ip = (const float4*)(expsc + base);
    float4* op = (float4*)(out2 + base);
    float4 x0 = ip[tid * 2];
    float4 x1 = ip[tid * 2 + 1];
    float4 y0 = {x0.x * inv, x0.y * inv, x0.z * inv, x0.w * inv};
    float4 y1 = {x1.x * inv, x1.y * inv, x1.z * inv, x1.w * inv};
    op[tid * 2] = y0;
    op[tid * 2 + 1] = y1;
  } else {
    const int h = bx - 4;
    float cs = 0.f;
#pragma unroll
    for (int j = 0; j < NBLK; ++j)
      cs += c_blk[((size_t)(b * NBLK + j)) * H_ + h];
    const float ctx = cs * inv;
    if (tid == 0) out1[b * H_ + h] = ctx;
    float4 vv = {ctx, ctx, ctx, ctx};
    float4* op = (float4*)(out0 + ((size_t)b * H_ + h) * S_);
#pragma unroll 4
    for (int i = tid; i < S_ / 4; i += 256) op[i] = vv;
  }
}

extern "C" void kernel_launch(void* const* d_in, const int* in_sizes, int n_in,
                              void* d_out, int out_size, void* d_ws,
                              size_t ws_size, hipStream_t stream) {
  const float* hidden = (const float*)d_in[0];
  const float* enc = (const float*)d_in[1];
  const float* W1 = (const float*)d_in[2];
  const float* W2 = (const float*)d_in[3];
  const float* V = (const float*)d_in[4];

  float* out0 = (float*)d_out;                // [B,H,S] context tiled
  float* out1 = out0 + (size_t)B_ * H_ * S_;  // [B,H]   context
  float* out2 = out1 + B_ * H_;               // [B,S]   attn

  float* ws = (float*)d_ws;
  short* W2f = (short*)ws;                 // 65536 shorts = 32768 floats
  float* h1 = ws + 32768;                  // 4096
  float* expsc = h1 + B_ * H_;             // B*S = 131072
  float* l_blk = expsc + (size_t)B_ * S_;  // 512
  float* c_blk = l_blk + B_ * NBLK;        // B*NBLK*H = 131072

  prep_kernel<<<48, 256, 0, stream>>>(hidden, W1, W2, W2f, h1);
  scores_ctx_kernel<<<B_ * NBLK, 512, 0, stream>>>(enc, W2f, h1, V, expsc,
                                                   c_blk, l_blk);
  finish_kernel<<<dim3(H_ + 4, B_), 256, 0, stream>>>(expsc, l_blk, c_blk,
                                                      out0, out1, out2);
}

// Round 10
// 76.648 us; speedup vs baseline: 1.1173x; 1.0512x over previous
//
#include <hip/hip_runtime.h>
#include <hip/hip_bf16.h>
#include <math.h>

#define B_ 16
#define S_ 8192
#define H_ 256
#define NBLK 32      // scores blocks per batch row
#define TILE_R 32    // s-rows per tile
#define T_PER_BLK 8  // tiles per block -> block covers 256 rows
#define LROW 264     // shorts per LDS row: 256 + 8 pad (132 dwords, 33 slots)

using bf16x8 = __attribute__((ext_vector_type(8))) short;
using f32x4 = __attribute__((ext_vector_type(4))) float;

// fp32 -> bf16 RNE (scalar, for prep one-time packing)
__device__ inline short f2bf(float x) {
  union {
    float f;
    unsigned u;
  } v;
  v.f = x;
  unsigned r = v.u + 0x7FFFu + ((v.u >> 16) & 1u);
  return (short)(r >> 16);
}

// pack 8 fp32 -> 8 bf16 via v_cvt_pk_bf16_f32
__device__ inline bf16x8 pack8(float4 a, float4 b) {
  union {
    __hip_bfloat162 h[4];
    bf16x8 v;
  } u;
  u.h[0] = __float22bfloat162_rn(make_float2(a.x, a.y));
  u.h[1] = __float22bfloat162_rn(make_float2(a.z, a.w));
  u.h[2] = __float22bfloat162_rn(make_float2(b.x, b.y));
  u.h[3] = __float22bfloat162_rn(make_float2(b.z, b.w));
  return u.v;
}

// tanh(x) = 1 - 2/(exp2(2x*log2e)+1)
__device__ inline float fast_tanh(float x) {
  float e = exp2f(x * 2.885390082f);
  return fmaf(-2.f, __builtin_amdgcn_rcpf(e + 1.f), 1.f);
}

// LDS-visibility-only barrier: does NOT drain vmcnt, so the next tile's
// staging global loads stay in flight across it (their data is consumed
// only by the issuing wave; the compiler inserts the precise vmcnt(N)
// at the pack8 use). All cross-wave deps here are LDS/shuffle -> covered
// by lgkmcnt(0).
__device__ inline void barrier_lgkm() {
  asm volatile("s_waitcnt lgkmcnt(0)" ::: "memory");
  __builtin_amdgcn_s_barrier();
}

// ---------------------------------------------------------------------------
// prep: blocks 0..31 pack W2 into MFMA B-fragment-major bf16; blocks 32..47:
// h1[b][k] = sum_h hidden[b][h]*W1[k][h]
// ---------------------------------------------------------------------------
__global__ __launch_bounds__(256) void prep_kernel(
    const float* __restrict__ hidden, const float* __restrict__ W1,
    const float* __restrict__ W2, short* __restrict__ W2f,
    float* __restrict__ h1) {
  const int blk = blockIdx.x;
  const int t = threadIdx.x;
  if (blk < 32) {
    const int gid = blk * 256 + t;  // 0..8191
    const int l = gid & 63;
    const int j0 = (gid >> 6) & 15;
    const int ks = gid >> 10;  // 0..7
    const int row = j0 * 16 + (l & 15);
    const int col = ks * 32 + (l >> 4) * 8;
    const float* wp = W2 + row * H_ + col;
    bf16x8 out;
#pragma unroll
    for (int i = 0; i < 8; ++i) out[i] = f2bf(wp[i]);
    *(bf16x8*)(W2f + (size_t)gid * 8) = out;
  } else {
    const int b = blk - 32;
    const float* hrow = hidden + b * H_;
    const float* wrow = W1 + t * H_;
    float acc = 0.f;
#pragma unroll 8
    for (int h = 0; h < H_; ++h) acc += hrow[h] * wrow[h];
    h1[b * H_ + t] = acc;
  }
}

// ---------------------------------------------------------------------------
// scores_ctx: fused GEMM + tanh/V-dot + UNNORMALIZED softmax-context.
// 512 thr = 8 waves, weight-stationary (wave w owns j0 {2w,2w+1} in regs).
// R6 structure exactly; only change: barriers are lgkm-only (no vmcnt drain).
//   MFMA(albuf[cur]) -> epilogue -> pcomb -> B1
//   -> [stage next tile into albuf[cur^1] || distributed combine -> avec]
//   -> B2 -> PV from albuf[cur] -> next iter.
// ---------------------------------------------------------------------------
__global__ __launch_bounds__(512, 4) void scores_ctx_kernel(
    const float* __restrict__ enc, const short* __restrict__ W2f,
    const float* __restrict__ h1, const float* __restrict__ V,
    float* __restrict__ expsc, float* __restrict__ c_blk,
    float* __restrict__ l_blk) {
  __shared__ __align__(16) short albuf[2][TILE_R * LROW];  // 2 x 16.5 KiB
  __shared__ float pcomb[8][33];
  __shared__ float avec[TILE_R];
  __shared__ float2 clds2[4][129];
  __shared__ float lsum[8];

  const int tid = threadIdx.x;
  const int w = tid >> 6;
  const int l = tid & 63;
  const int lo = l & 15;
  const int hi = l >> 4;
  const int bid = blockIdx.x;
  const int b = bid >> 5;
  const int blk = bid & 31;
  const int s_base = blk * (TILE_R * T_PER_BLK);

  // --- one-time: B fragments into registers (j0 = 2w, 2w+1) ---
  const bf16x8* bbase = (const bf16x8*)W2f;
  bf16x8 bfrag[8][2];
#pragma unroll
  for (int ks = 0; ks < 8; ++ks)
#pragma unroll
    for (int jj = 0; jj < 2; ++jj)
      bfrag[ks][jj] = bbase[(ks * 16 + (2 * w + jj)) * 64 + l];

  float h1v[2], Vv[2];
#pragma unroll
  for (int jj = 0; jj < 2; ++jj) {
    h1v[jj] = h1[b * H_ + (2 * w + jj) * 16 + lo];
    Vv[jj] = V[(2 * w + jj) * 16 + lo];
  }

  // staging ids: thread covers rows r0, r0+16 at col chunk kc0*8
  const int r0 = tid >> 5;   // 0..15
  const int kc0 = tid & 31;  // 8-float col chunk
  const float4* gsrc = (const float4*)(enc + (size_t)b * S_ * H_);

  // PV ids: thread covers dword-col cp (h = 2cp, 2cp+1), rows rg*8..rg*8+7
  const int rg = tid >> 7;   // 0..3
  const int cp = tid & 127;  // dword column
  float c0 = 0.f, c1 = 0.f, l_part = 0.f;

  // prologue: stage tile 0
  {
    size_t gi0 = ((size_t)(s_base + r0) * (H_ / 4)) + kc0 * 2;
    size_t gi1 = ((size_t)(s_base + r0 + 16) * (H_ / 4)) + kc0 * 2;
    float4 a0 = gsrc[gi0], a1 = gsrc[gi0 + 1];
    float4 b0 = gsrc[gi1], b1 = gsrc[gi1 + 1];
    *(bf16x8*)&albuf[0][r0 * LROW + kc0 * 8] = pack8(a0, a1);
    *(bf16x8*)&albuf[0][(r0 + 16) * LROW + kc0 * 8] = pack8(b0, b1);
  }
  barrier_lgkm();

  const int b0s = lo & 1;
  const int b1s = (lo >> 1) & 1;
  const int b2s = (lo >> 2) & 1;

  for (int t = 0; t < T_PER_BLK; ++t) {
    const int cur = t & 1;

    // issue next tile's global loads (stay in flight across B1)
    float4 na0, na1, nb0, nb1;
    if (t + 1 < T_PER_BLK) {
      size_t gi0 =
          ((size_t)(s_base + (t + 1) * TILE_R + r0) * (H_ / 4)) + kc0 * 2;
      size_t gi1 =
          ((size_t)(s_base + (t + 1) * TILE_R + r0 + 16) * (H_ / 4)) + kc0 * 2;
      na0 = gsrc[gi0];
      na1 = gsrc[gi0 + 1];
      nb0 = gsrc[gi1];
      nb1 = gsrc[gi1 + 1];
    }

    // --- MFMA phase: A from LDS, B from regs ---
    f32x4 acc[2][2];
#pragma unroll
    for (int m = 0; m < 2; ++m)
#pragma unroll
      for (int jj = 0; jj < 2; ++jj) acc[m][jj] = (f32x4){0.f, 0.f, 0.f, 0.f};

    const short* abase = &albuf[cur][lo * LROW + hi * 8];
#pragma unroll
    for (int ks = 0; ks < 8; ++ks) {
      bf16x8 a0 = *(const bf16x8*)(abase + ks * 32);
      bf16x8 a1 = *(const bf16x8*)(abase + 16 * LROW + ks * 32);
      acc[0][0] = __builtin_amdgcn_mfma_f32_16x16x32_bf16(a0, bfrag[ks][0], acc[0][0], 0, 0, 0);
      acc[0][1] = __builtin_amdgcn_mfma_f32_16x16x32_bf16(a0, bfrag[ks][1], acc[0][1], 0, 0, 0);
      acc[1][0] = __builtin_amdgcn_mfma_f32_16x16x32_bf16(a1, bfrag[ks][0], acc[1][0], 0, 0, 0);
      acc[1][1] = __builtin_amdgcn_mfma_f32_16x16x32_bf16(a1, bfrag[ks][1], acc[1][1], 0, 0, 0);
    }

    // --- epilogue: tanh + V-dot, 8-shfl value-split 16-lane reduce ---
    float p0 = fast_tanh(acc[0][0][0] + h1v[0]) * Vv[0] + fast_tanh(acc[0][1][0] + h1v[1]) * Vv[1];
    float p1 = fast_tanh(acc[0][0][1] + h1v[0]) * Vv[0] + fast_tanh(acc[0][1][1] + h1v[1]) * Vv[1];
    float p2 = fast_tanh(acc[0][0][2] + h1v[0]) * Vv[0] + fast_tanh(acc[0][1][2] + h1v[1]) * Vv[1];
    float p3 = fast_tanh(acc[0][0][3] + h1v[0]) * Vv[0] + fast_tanh(acc[0][1][3] + h1v[1]) * Vv[1];
    float p4 = fast_tanh(acc[1][0][0] + h1v[0]) * Vv[0] + fast_tanh(acc[1][1][0] + h1v[1]) * Vv[1];
    float p5 = fast_tanh(acc[1][0][1] + h1v[0]) * Vv[0] + fast_tanh(acc[1][1][1] + h1v[1]) * Vv[1];
    float p6 = fast_tanh(acc[1][0][2] + h1v[0]) * Vv[0] + fast_tanh(acc[1][1][2] + h1v[1]) * Vv[1];
    float p7 = fast_tanh(acc[1][0][3] + h1v[0]) * Vv[0] + fast_tanh(acc[1][1][3] + h1v[1]) * Vv[1];

    float q0 = (b0s ? p1 : p0) + __shfl_xor((b0s ? p0 : p1), 1, 16);
    float q1 = (b0s ? p3 : p2) + __shfl_xor((b0s ? p2 : p3), 1, 16);
    float q2 = (b0s ? p5 : p4) + __shfl_xor((b0s ? p4 : p5), 1, 16);
    float q3 = (b0s ? p7 : p6) + __shfl_xor((b0s ? p6 : p7), 1, 16);
    float r0q = (b1s ? q1 : q0) + __shfl_xor((b1s ? q0 : q1), 2, 16);
    float r1q = (b1s ? q3 : q2) + __shfl_xor((b1s ? q2 : q3), 2, 16);
    float u = (b2s ? r1q : r0q) + __shfl_xor((b2s ? r0q : r1q), 4, 16);
    u += __shfl_xor(u, 8, 16);

    if (lo < 8) {
      const int row = ((lo >> 2) & 1) * 16 + hi * 4 + (lo & 3);
      pcomb[w][row] = u;
    }
    barrier_lgkm();  // B1: pcomb ready; staging loads still in flight

    // stage next tile (vmcnt wait lands here, at the pack8 use)
    if (t + 1 < T_PER_BLK) {
      *(bf16x8*)&albuf[cur ^ 1][r0 * LROW + kc0 * 8] = pack8(na0, na1);
      *(bf16x8*)&albuf[cur ^ 1][(r0 + 16) * LROW + kc0 * 8] = pack8(nb0, nb1);
    }

    // distributed combine: wave w, lanes 0..3 -> rows 4w..4w+3
    if (l < 4) {
      const int row = w * 4 + l;
      float s = 0.f;
#pragma unroll
      for (int ww = 0; ww < 8; ++ww) s += pcomb[ww][row];
      float e = exp2f(s * 1.44269504f);
      avec[row] = e;
      expsc[(size_t)b * S_ + s_base + t * TILE_R + row] = e;
      l_part += e;
    }
    barrier_lgkm();  // B2: avec + staged buffer ready

    // --- PV: c[h] += exp(s) * enc_bf16[s][h] from albuf[cur] ---
    const unsigned* ab32 = (const unsigned*)&albuf[cur][0];
#pragma unroll
    for (int k = 0; k < 8; ++k) {
      const int r = rg * 8 + k;
      unsigned vb = ab32[r * 132 + cp];
      float a = avec[r];
      float he = __uint_as_float(vb << 16);
      float ho = __uint_as_float(vb & 0xFFFF0000u);
      c0 = fmaf(a, he, c0);
      c1 = fmaf(a, ho, c1);
    }
    // no barrier: PV(t) reads complete before this wave's B1(t+1), and
    // stage(t+1) into albuf[cur] happens only after B1(t+1).
  }

  // --- final combines ---
  float lp = l_part;  // nonzero only in lanes 0..3 of each wave
  lp += __shfl_xor(lp, 1);
  lp += __shfl_xor(lp, 2);
  if (l == 0) lsum[w] = lp;
  clds2[rg][cp] = make_float2(c0, c1);
  barrier_lgkm();
  if (tid < 128) {
    float2 s0 = clds2[0][tid], s1 = clds2[1][tid];
    float2 s2 = clds2[2][tid], s3 = clds2[3][tid];
    float2 r;
    r.x = s0.x + s1.x + s2.x + s3.x;
    r.y = s0.y + s1.y + s2.y + s3.y;
    ((float2*)(c_blk + ((size_t)(b * NBLK + blk)) * H_))[tid] = r;
  }
  if (tid == 0) {
    float ls = 0.f;
#pragma unroll
    for (int ww = 0; ww < 8; ++ww) ls += lsum[ww];
    l_blk[b * NBLK + blk] = ls;
  }
}

// ---------------------------------------------------------------------------
// finish: grid (260, B). bx<4: attn-norm chunk (out2 = expsc/lg);
// bx>=4: h = bx-4: ctx = sum_blk c_blk/lg -> out1 + broadcast out0 row.
// ---------------------------------------------------------------------------
__global__ __launch_bounds__(256) void finish_kernel(
    const float* __restrict__ expsc, const float* __restrict__ l_blk,
    const float* __restrict__ c_blk, float* __restrict__ out0,
    float* __restrict__ out1, float* __restrict__ out2) {
  const int bx = blockIdx.x;
  const int b = blockIdx.y;
  const int tid = threadIdx.x;
  float lg = 0.f;
#pragma unroll
  for (int j = 0; j < NBLK; ++j) lg += l_blk[b * NBLK + j];
  const float inv = 1.f / lg;

  if (bx < 4) {
    const size_t base = (size_t)b * S_ + bx * 2048;
    const float4* ip = (const float4*)(expsc + base);
    float4* op = (float4*)(out2 + base);
    float4 x0 = ip[tid * 2];
    float4 x1 = ip[tid * 2 + 1];
    float4 y0 = {x0.x * inv, x0.y * inv, x0.z * inv, x0.w * inv};
    float4 y1 = {x1.x * inv, x1.y * inv, x1.z * inv, x1.w * inv};
    op[tid * 2] = y0;
    op[tid * 2 + 1] = y1;
  } else {
    const int h = bx - 4;
    float cs = 0.f;
#pragma unroll
    for (int j = 0; j < NBLK; ++j)
      cs += c_blk[((size_t)(b * NBLK + j)) * H_ + h];
    const float ctx = cs * inv;
    if (tid == 0) out1[b * H_ + h] = ctx;
    float4 vv = {ctx, ctx, ctx, ctx};
    float4* op = (float4*)(out0 + ((size_t)b * H_ + h) * S_);
#pragma unroll 4
    for (int i = tid; i < S_ / 4; i += 256) op[i] = vv;
  }
}

extern "C" void kernel_launch(void* const* d_in, const int* in_sizes, int n_in,
                              void* d_out, int out_size, void* d_ws,
                              size_t ws_size, hipStream_t stream) {
  const float* hidden = (const float*)d_in[0];
  const float* enc = (const float*)d_in[1];
  const float* W1 = (const float*)d_in[2];
  const float* W2 = (const float*)d_in[3];
  const float* V = (const float*)d_in[4];

  float* out0 = (float*)d_out;                // [B,H,S] context tiled
  float* out1 = out0 + (size_t)B_ * H_ * S_;  // [B,H]   context
  float* out2 = out1 + B_ * H_;               // [B,S]   attn

  float* ws = (float*)d_ws;
  short* W2f = (short*)ws;                 // 65536 shorts = 32768 floats
  float* h1 = ws + 32768;                  // 4096
  float* expsc = h1 + B_ * H_;             // B*S = 131072
  float* l_blk = expsc + (size_t)B_ * S_;  // 512
  float* c_blk = l_blk + B_ * NBLK;        // B*NBLK*H = 131072

  prep_kernel<<<48, 256, 0, stream>>>(hidden, W1, W2, W2f, h1);
  scores_ctx_kernel<<<B_ * NBLK, 512, 0, stream>>>(enc, W2f, h1, V, expsc,
                                                   c_blk, l_blk);
  finish_kernel<<<dim3(H_ + 4, B_), 256, 0, stream>>>(expsc, l_blk, c_blk,
                                                      out0, out1, out2);
}

// Round 11
// 75.097 us; speedup vs baseline: 1.1404x; 1.0207x over previous
//
#include <hip/hip_runtime.h>
#include <hip/hip_bf16.h>
#include <math.h>

#define B_ 16
#define S_ 8192
#define H_ 256
#define NBLK 32      // scores blocks per batch row
#define TILE_R 32    // s-rows per tile
#define T_PER_BLK 8  // tiles per block -> block covers 256 rows
#define LROW 264     // shorts per LDS row: 256 + 8 pad (132 dwords, 33 slots)

using bf16x8 = __attribute__((ext_vector_type(8))) short;
using f32x4 = __attribute__((ext_vector_type(4))) float;

// fp32 -> bf16 RNE (scalar, for prep one-time packing)
__device__ inline short f2bf(float x) {
  union {
    float f;
    unsigned u;
  } v;
  v.f = x;
  unsigned r = v.u + 0x7FFFu + ((v.u >> 16) & 1u);
  return (short)(r >> 16);
}

// pack 8 fp32 -> 8 bf16 via v_cvt_pk_bf16_f32
__device__ inline bf16x8 pack8(float4 a, float4 b) {
  union {
    __hip_bfloat162 h[4];
    bf16x8 v;
  } u;
  u.h[0] = __float22bfloat162_rn(make_float2(a.x, a.y));
  u.h[1] = __float22bfloat162_rn(make_float2(a.z, a.w));
  u.h[2] = __float22bfloat162_rn(make_float2(b.x, b.y));
  u.h[3] = __float22bfloat162_rn(make_float2(b.z, b.w));
  return u.v;
}

// tanh(x) = 1 - 2/(exp2(2x*log2e)+1)
__device__ inline float fast_tanh(float x) {
  float e = exp2f(x * 2.885390082f);
  return fmaf(-2.f, __builtin_amdgcn_rcpf(e + 1.f), 1.f);
}

// ---------------------------------------------------------------------------
// prep: blocks 0..31 pack W2 into MFMA B-fragment-major bf16; blocks 32..47:
// h1[b][k] = sum_h hidden[b][h]*W1[k][h]
// ---------------------------------------------------------------------------
__global__ __launch_bounds__(256) void prep_kernel(
    const float* __restrict__ hidden, const float* __restrict__ W1,
    const float* __restrict__ W2, short* __restrict__ W2f,
    float* __restrict__ h1) {
  const int blk = blockIdx.x;
  const int t = threadIdx.x;
  if (blk < 32) {
    const int gid = blk * 256 + t;  // 0..8191
    const int l = gid & 63;
    const int j0 = (gid >> 6) & 15;
    const int ks = gid >> 10;  // 0..7
    const int row = j0 * 16 + (l & 15);
    const int col = ks * 32 + (l >> 4) * 8;
    const float* wp = W2 + row * H_ + col;
    bf16x8 out;
#pragma unroll
    for (int i = 0; i < 8; ++i) out[i] = f2bf(wp[i]);
    *(bf16x8*)(W2f + (size_t)gid * 8) = out;
  } else {
    const int b = blk - 32;
    const float* hrow = hidden + b * H_;
    const float* wrow = W1 + t * H_;
    float acc = 0.f;
#pragma unroll 8
    for (int h = 0; h < H_; ++h) acc += hrow[h] * wrow[h];
    h1[b * H_ + t] = acc;
  }
}

// ---------------------------------------------------------------------------
// scores_ctx: fused GEMM + tanh/V-dot + UNNORMALIZED softmax-context.
// 512 thr = 8 waves, weight-stationary (wave w owns j0 {2w,2w+1} in regs).
// R6 structure; ONLY change vs R6: the next-tile staging loads are issued
// AFTER the MFMA loop (not at loop top), shrinking their live range from
// ~1500 cyc (across MFMA+epilogue) to ~400 (epilogue only) -> register
// peak drops ~16 VGPR below the __launch_bounds__(512,4) 128 cap, removing
// hot-loop scratch spills. Their L2/L3 latency hides under the epilogue.
//   MFMA(albuf[cur]) -> issue loads(t+1) -> epilogue -> pcomb -> B1
//   -> [stage(t+1) -> albuf[cur^1] || distributed combine -> avec]
//   -> B2 -> PV from albuf[cur] -> next iter.
// ---------------------------------------------------------------------------
__global__ __launch_bounds__(512, 4) void scores_ctx_kernel(
    const float* __restrict__ enc, const short* __restrict__ W2f,
    const float* __restrict__ h1, const float* __restrict__ V,
    float* __restrict__ expsc, float* __restrict__ c_blk,
    float* __restrict__ l_blk) {
  __shared__ __align__(16) short albuf[2][TILE_R * LROW];  // 2 x 16.5 KiB
  __shared__ float pcomb[8][33];
  __shared__ float avec[TILE_R];
  __shared__ float2 clds2[4][129];
  __shared__ float lsum[8];

  const int tid = threadIdx.x;
  const int w = tid >> 6;
  const int l = tid & 63;
  const int lo = l & 15;
  const int hi = l >> 4;
  const int bid = blockIdx.x;
  const int b = bid >> 5;
  const int blk = bid & 31;
  const int s_base = blk * (TILE_R * T_PER_BLK);

  // --- one-time: B fragments into registers (j0 = 2w, 2w+1) ---
  const bf16x8* bbase = (const bf16x8*)W2f;
  bf16x8 bfrag[8][2];
#pragma unroll
  for (int ks = 0; ks < 8; ++ks)
#pragma unroll
    for (int jj = 0; jj < 2; ++jj)
      bfrag[ks][jj] = bbase[(ks * 16 + (2 * w + jj)) * 64 + l];

  float h1v[2], Vv[2];
#pragma unroll
  for (int jj = 0; jj < 2; ++jj) {
    h1v[jj] = h1[b * H_ + (2 * w + jj) * 16 + lo];
    Vv[jj] = V[(2 * w + jj) * 16 + lo];
  }

  // staging ids: thread covers rows r0, r0+16 at col chunk kc0*8
  const int r0 = tid >> 5;   // 0..15
  const int kc0 = tid & 31;  // 8-float col chunk
  const float4* gsrc = (const float4*)(enc + (size_t)b * S_ * H_);
  // 32-bit float4 index of (row, chunk): row*64 + kc0*2  (max 524288)
  const int gbase = r0 * 64 + kc0 * 2;

  // PV ids: thread covers dword-col cp (h = 2cp, 2cp+1), rows rg*8..rg*8+7
  const int rg = tid >> 7;   // 0..3
  const int cp = tid & 127;  // dword column
  float c0 = 0.f, c1 = 0.f, l_part = 0.f;

  // prologue: stage tile 0
  {
    const int gi0 = s_base * 64 + gbase;
    const int gi1 = gi0 + 16 * 64;
    float4 a0 = gsrc[gi0], a1 = gsrc[gi0 + 1];
    float4 b0 = gsrc[gi1], b1 = gsrc[gi1 + 1];
    *(bf16x8*)&albuf[0][r0 * LROW + kc0 * 8] = pack8(a0, a1);
    *(bf16x8*)&albuf[0][(r0 + 16) * LROW + kc0 * 8] = pack8(b0, b1);
  }
  __syncthreads();

  const int b0s = lo & 1;
  const int b1s = (lo >> 1) & 1;
  const int b2s = (lo >> 2) & 1;

  for (int t = 0; t < T_PER_BLK; ++t) {
    const int cur = t & 1;

    // --- MFMA phase: A from LDS, B from regs ---
    f32x4 acc[2][2];
#pragma unroll
    for (int m = 0; m < 2; ++m)
#pragma unroll
      for (int jj = 0; jj < 2; ++jj) acc[m][jj] = (f32x4){0.f, 0.f, 0.f, 0.f};

    const short* abase = &albuf[cur][lo * LROW + hi * 8];
#pragma unroll
    for (int ks = 0; ks < 8; ++ks) {
      bf16x8 a0 = *(const bf16x8*)(abase + ks * 32);
      bf16x8 a1 = *(const bf16x8*)(abase + 16 * LROW + ks * 32);
      acc[0][0] = __builtin_amdgcn_mfma_f32_16x16x32_bf16(a0, bfrag[ks][0], acc[0][0], 0, 0, 0);
      acc[0][1] = __builtin_amdgcn_mfma_f32_16x16x32_bf16(a0, bfrag[ks][1], acc[0][1], 0, 0, 0);
      acc[1][0] = __builtin_amdgcn_mfma_f32_16x16x32_bf16(a1, bfrag[ks][0], acc[1][0], 0, 0, 0);
      acc[1][1] = __builtin_amdgcn_mfma_f32_16x16x32_bf16(a1, bfrag[ks][1], acc[1][1], 0, 0, 0);
    }

    // issue next tile's loads NOW (short live range; latency hides under
    // the epilogue; consumed at pack8 after B1)
    float4 na0, na1, nb0, nb1;
    if (t + 1 < T_PER_BLK) {
      const int gi0 = (s_base + (t + 1) * TILE_R) * 64 + gbase;
      const int gi1 = gi0 + 16 * 64;
      na0 = gsrc[gi0];
      na1 = gsrc[gi0 + 1];
      nb0 = gsrc[gi1];
      nb1 = gsrc[gi1 + 1];
    }

    // --- epilogue: tanh + V-dot, 8-shfl value-split 16-lane reduce ---
    float p0 = fast_tanh(acc[0][0][0] + h1v[0]) * Vv[0] + fast_tanh(acc[0][1][0] + h1v[1]) * Vv[1];
    float p1 = fast_tanh(acc[0][0][1] + h1v[0]) * Vv[0] + fast_tanh(acc[0][1][1] + h1v[1]) * Vv[1];
    float p2 = fast_tanh(acc[0][0][2] + h1v[0]) * Vv[0] + fast_tanh(acc[0][1][2] + h1v[1]) * Vv[1];
    float p3 = fast_tanh(acc[0][0][3] + h1v[0]) * Vv[0] + fast_tanh(acc[0][1][3] + h1v[1]) * Vv[1];
    float p4 = fast_tanh(acc[1][0][0] + h1v[0]) * Vv[0] + fast_tanh(acc[1][1][0] + h1v[1]) * Vv[1];
    float p5 = fast_tanh(acc[1][0][1] + h1v[0]) * Vv[0] + fast_tanh(acc[1][1][1] + h1v[1]) * Vv[1];
    float p6 = fast_tanh(acc[1][0][2] + h1v[0]) * Vv[0] + fast_tanh(acc[1][1][2] + h1v[1]) * Vv[1];
    float p7 = fast_tanh(acc[1][0][3] + h1v[0]) * Vv[0] + fast_tanh(acc[1][1][3] + h1v[1]) * Vv[1];

    float q0 = (b0s ? p1 : p0) + __shfl_xor((b0s ? p0 : p1), 1, 16);
    float q1 = (b0s ? p3 : p2) + __shfl_xor((b0s ? p2 : p3), 1, 16);
    float q2 = (b0s ? p5 : p4) + __shfl_xor((b0s ? p4 : p5), 1, 16);
    float q3 = (b0s ? p7 : p6) + __shfl_xor((b0s ? p6 : p7), 1, 16);
    float r0q = (b1s ? q1 : q0) + __shfl_xor((b1s ? q0 : q1), 2, 16);
    float r1q = (b1s ? q3 : q2) + __shfl_xor((b1s ? q2 : q3), 2, 16);
    float u = (b2s ? r1q : r0q) + __shfl_xor((b2s ? r0q : r1q), 4, 16);
    u += __shfl_xor(u, 8, 16);

    if (lo < 8) {
      const int row = ((lo >> 2) & 1) * 16 + hi * 4 + (lo & 3);
      pcomb[w][row] = u;
    }
    __syncthreads();  // B1: pcomb ready

    // stage next tile (loads consumed here; vmcnt wait lands at pack8)
    if (t + 1 < T_PER_BLK) {
      *(bf16x8*)&albuf[cur ^ 1][r0 * LROW + kc0 * 8] = pack8(na0, na1);
      *(bf16x8*)&albuf[cur ^ 1][(r0 + 16) * LROW + kc0 * 8] = pack8(nb0, nb1);
    }

    // distributed combine: wave w, lanes 0..3 -> rows 4w..4w+3
    if (l < 4) {
      const int row = w * 4 + l;
      float s = 0.f;
#pragma unroll
      for (int ww = 0; ww < 8; ++ww) s += pcomb[ww][row];
      float e = exp2f(s * 1.44269504f);
      avec[row] = e;
      expsc[(size_t)b * S_ + s_base + t * TILE_R + row] = e;
      l_part += e;
    }
    __syncthreads();  // B2: avec + staged buffer ready

    // --- PV: c[h] += exp(s) * enc_bf16[s][h] from albuf[cur] ---
    const unsigned* ab32 = (const unsigned*)&albuf[cur][0];
#pragma unroll
    for (int k = 0; k < 8; ++k) {
      const int r = rg * 8 + k;
      unsigned vb = ab32[r * 132 + cp];
      float a = avec[r];
      float he = __uint_as_float(vb << 16);
      float ho = __uint_as_float(vb & 0xFFFF0000u);
      c0 = fmaf(a, he, c0);
      c1 = fmaf(a, ho, c1);
    }
    // no barrier: PV(t) reads complete before this wave's B1(t+1), and
    // stage(t+1) into albuf[cur] happens only after B1(t+1).
  }

  // --- final combines ---
  float lp = l_part;  // nonzero only in lanes 0..3 of each wave
  lp += __shfl_xor(lp, 1);
  lp += __shfl_xor(lp, 2);
  if (l == 0) lsum[w] = lp;
  clds2[rg][cp] = make_float2(c0, c1);
  __syncthreads();
  if (tid < 128) {
    float2 s0 = clds2[0][tid], s1 = clds2[1][tid];
    float2 s2 = clds2[2][tid], s3 = clds2[3][tid];
    float2 r;
    r.x = s0.x + s1.x + s2.x + s3.x;
    r.y = s0.y + s1.y + s2.y + s3.y;
    ((float2*)(c_blk + ((size_t)(b * NBLK + blk)) * H_))[tid] = r;
  }
  if (tid == 0) {
    float ls = 0.f;
#pragma unroll
    for (int ww = 0; ww < 8; ++ww) ls += lsum[ww];
    l_blk[b * NBLK + blk] = ls;
  }
}

// ---------------------------------------------------------------------------
// finish: grid (260, B). bx<4: attn-norm chunk (out2 = expsc/lg);
// bx>=4: h = bx-4: ctx = sum_blk c_blk/lg -> out1 + broadcast out0 row.
// ---------------------------------------------------------------------------
__global__ __launch_bounds__(256) void finish_kernel(
    const float* __restrict__ expsc, const float* __restrict__ l_blk,
    const float* __restrict__ c_blk, float* __restrict__ out0,
    float* __restrict__ out1, float* __restrict__ out2) {
  const int bx = blockIdx.x;
  const int b = blockIdx.y;
  const int tid = threadIdx.x;
  float lg = 0.f;
#pragma unroll
  for (int j = 0; j < NBLK; ++j) lg += l_blk[b * NBLK + j];
  const float inv = 1.f / lg;

  if (bx < 4) {
    const size_t base = (size_t)b * S_ + bx * 2048;
    const float4* ip = (const float4*)(expsc + base);
    float4* op = (float4*)(out2 + base);
    float4 x0 = ip[tid * 2];
    float4 x1 = ip[tid * 2 + 1];
    float4 y0 = {x0.x * inv, x0.y * inv, x0.z * inv, x0.w * inv};
    float4 y1 = {x1.x * inv, x1.y * inv, x1.z * inv, x1.w * inv};
    op[tid * 2] = y0;
    op[tid * 2 + 1] = y1;
  } else {
    const int h = bx - 4;
    float cs = 0.f;
#pragma unroll
    for (int j = 0; j < NBLK; ++j)
      cs += c_blk[((size_t)(b * NBLK + j)) * H_ + h];
    const float ctx = cs * inv;
    if (tid == 0) out1[b * H_ + h] = ctx;
    float4 vv = {ctx, ctx, ctx, ctx};
    float4* op = (float4*)(out0 + ((size_t)b * H_ + h) * S_);
#pragma unroll 4
    for (int i = tid; i < S_ / 4; i += 256) op[i] = vv;
  }
}

extern "C" void kernel_launch(void* const* d_in, const int* in_sizes, int n_in,
                              void* d_out, int out_size, void* d_ws,
                              size_t ws_size, hipStream_t stream) {
  const float* hidden = (const float*)d_in[0];
  const float* enc = (const float*)d_in[1];
  const float* W1 = (const float*)d_in[2];
  const float* W2 = (const float*)d_in[3];
  const float* V = (const float*)d_in[4];

  float* out0 = (float*)d_out;                // [B,H,S] context tiled
  float* out1 = out0 + (size_t)B_ * H_ * S_;  // [B,H]   context
  float* out2 = out1 + B_ * H_;               // [B,S]   attn

  float* ws = (float*)d_ws;
  short* W2f = (short*)ws;                 // 65536 shorts = 32768 floats
  float* h1 = ws + 32768;                  // 4096
  float* expsc = h1 + B_ * H_;             // B*S = 131072
  float* l_blk = expsc + (size_t)B_ * S_;  // 512
  float* c_blk = l_blk + B_ * NBLK;        // B*NBLK*H = 131072

  prep_kernel<<<48, 256, 0, stream>>>(hidden, W1, W2, W2f, h1);
  scores_ctx_kernel<<<B_ * NBLK, 512, 0, stream>>>(enc, W2f, h1, V, expsc,
                                                   c_blk, l_blk);
  finish_kernel<<<dim3(H_ + 4, B_), 256, 0, stream>>>(expsc, l_blk, c_blk,
                                                      out0, out1, out2);
}